// Round 4
// baseline (746.724 us; speedup 1.0000x reference)
//
#include <hip/hip_runtime.h>
#include <hip/hip_bf16.h>
#include <math.h>

typedef __bf16 bf16_t;
typedef __bf16 bf16x8 __attribute__((ext_vector_type(8)));
typedef __bf16 bf16x4v __attribute__((ext_vector_type(4)));
typedef float  f32x4  __attribute__((ext_vector_type(4)));

constexpr int CB = 4, CS = 2048, CH = 2048, CNH = 16, CHD = 128;
constexpr int CM = CB * CS;  // 8192 rows of x
constexpr float CSCALE = 0.08838834764831845f;  // 128^-0.5
constexpr float CL2E   = 1.4426950408889634f;

// async global->LDS, 16B per lane. LDS dest is wave-uniform base (+lane*16 by HW).
__device__ __forceinline__ void g2l16(const void* g, void* l) {
  __builtin_amdgcn_global_load_lds(
      (const __attribute__((address_space(1))) void*)g,
      (__attribute__((address_space(3))) void*)l, 16, 0, 0);
}

// ---------------- f32 -> bf16 conversion (vectorized) ----------------
__global__ __launch_bounds__(256) void cvt_kernel(const float* __restrict__ in,
                                                  bf16_t* __restrict__ out, int n4) {
  int i = blockIdx.x * 256 + threadIdx.x;
  if (i >= n4) return;
  float4 v = reinterpret_cast<const float4*>(in)[i];
  bf16x4v o = {(bf16_t)v.x, (bf16_t)v.y, (bf16_t)v.z, (bf16_t)v.w};
  reinterpret_cast<bf16x4v*>(out)[i] = o;
}

// ================= 256x128 BK=64 triple-buffered GEMM core =================
// 8 waves (512 thr) as 4M x 2N; per-wave C = 64x64 (4m x 4n frags).
// LDS slots rotate %3: consume slot t%3 while staging tile t+2 into (t+2)%3
// (that slot was freed at the top-of-t barrier). Counted vmcnt(6) per tile.
// Chunk-XOR swizzle (c ^= row&7) applied to BOTH the pre-swizzled global
// source of global_load_lds and the ds_read chunk index (involution).
// K-slice kk (32 cols) of a 64-col row = chunks [kk*4, kk*4+4); lane sub-chunk
// chi = lane>>4 -> logical chunk = kk*4 + chi.  (R3 bug: had kk*2+chi.)
__device__ __forceinline__ bf16x8 lds_frag(const bf16_t* base, int row, int c) {
  return *(const bf16x8*)(base + row * 64 + ((c ^ (row & 7)) << 3));
}

__device__ __forceinline__ void gemm256_core(const bf16_t* __restrict__ A,
                                             const bf16_t* __restrict__ Bm,
                                             bf16_t (*As3)[256 * 64],
                                             bf16_t (*Bs3)[128 * 64],
                                             int row0, int col0,
                                             f32x4 (&acc)[4][4]) {
  const int tid = threadIdx.x, lane = tid & 63, w = tid >> 6;
  const int wm = w >> 1, wn = w & 1;
  constexpr int NKT = CH / 64;  // 32 K-tiles

  auto stageA = [&](int slot, int kt, int r) {  // A tile: 256x64 = 2048 chunks, 4 rounds
    const int id = r * 512 + w * 64 + lane;
    const int row = id >> 3, ck = id & 7;
    g2l16(A + (size_t)(row0 + row) * CH + kt * 64 + ((ck ^ (row & 7)) << 3),
          As3[slot] + (size_t)(r * 512 + w * 64) * 8);
  };
  auto stageB = [&](int slot, int kt, int r) {  // B tile: 128x64 = 1024 chunks, 2 rounds
    const int id = r * 512 + w * 64 + lane;
    const int row = id >> 3, ck = id & 7;
    g2l16(Bm + (size_t)(col0 + row) * CH + kt * 64 + ((ck ^ (row & 7)) << 3),
          Bs3[slot] + (size_t)(r * 512 + w * 64) * 8);
  };

  // prologue: stage tiles 0 and 1 (6 loads/thread each)
#pragma unroll
  for (int r = 0; r < 4; ++r) stageA(0, 0, r);
#pragma unroll
  for (int r = 0; r < 2; ++r) stageB(0, 0, r);
#pragma unroll
  for (int r = 0; r < 4; ++r) stageA(1, 1, r);
#pragma unroll
  for (int r = 0; r < 2; ++r) stageB(1, 1, r);

  bf16x8 aa[2][2], bb[4][2];
  const int arow = wm * 64 + (lane & 15);
  const int brow = wn * 64 + (lane & 15);
  const int chi = lane >> 4;  // chunk sub-index from lane

  for (int t = 0; t < NKT; ++t) {
    const int slot = t % 3, nslot = (t + 2) % 3;
    // boundary: tile t's loads must have landed; tile t+1's 6 stay in flight
    if (t < NKT - 1) {
      asm volatile("s_waitcnt vmcnt(6)" ::: "memory");
    } else {
      asm volatile("s_waitcnt vmcnt(0)" ::: "memory");
    }
    __builtin_amdgcn_s_barrier();
    __builtin_amdgcn_sched_barrier(0);
    const bf16_t* Asl = As3[slot];
    const bf16_t* Bsl = Bs3[slot];
    const bool pf = (t + 2 < NKT);

    // ---- phase 0: quadrant (m0-1, n0-1); stage A r0,r1 ----
    if (pf) { stageA(nslot, t + 2, 0); stageA(nslot, t + 2, 1); }
#pragma unroll
    for (int i = 0; i < 2; ++i)
#pragma unroll
      for (int kk = 0; kk < 2; ++kk) {
        aa[i][kk] = lds_frag(Asl, arow + i * 16, kk * 4 + chi);
        bb[i][kk] = lds_frag(Bsl, brow + i * 16, kk * 4 + chi);
      }
    asm volatile("s_waitcnt lgkmcnt(0)" ::: "memory");
    __builtin_amdgcn_sched_barrier(0);
    __builtin_amdgcn_s_setprio(1);
#pragma unroll
    for (int i = 0; i < 2; ++i)
#pragma unroll
      for (int j = 0; j < 2; ++j)
#pragma unroll
        for (int kk = 0; kk < 2; ++kk)
          acc[i][j] = __builtin_amdgcn_mfma_f32_16x16x32_bf16(aa[i][kk], bb[j][kk], acc[i][j], 0, 0, 0);
    __builtin_amdgcn_s_setprio(0);
    __builtin_amdgcn_s_barrier();

    // ---- phase 1: quadrant (m0-1, n2-3); stage A r2,r3 ----
    if (pf) { stageA(nslot, t + 2, 2); stageA(nslot, t + 2, 3); }
#pragma unroll
    for (int j = 2; j < 4; ++j)
#pragma unroll
      for (int kk = 0; kk < 2; ++kk)
        bb[j][kk] = lds_frag(Bsl, brow + j * 16, kk * 4 + chi);
    asm volatile("s_waitcnt lgkmcnt(0)" ::: "memory");
    __builtin_amdgcn_sched_barrier(0);
    __builtin_amdgcn_s_setprio(1);
#pragma unroll
    for (int i = 0; i < 2; ++i)
#pragma unroll
      for (int j = 2; j < 4; ++j)
#pragma unroll
        for (int kk = 0; kk < 2; ++kk)
          acc[i][j] = __builtin_amdgcn_mfma_f32_16x16x32_bf16(aa[i][kk], bb[j][kk], acc[i][j], 0, 0, 0);
    __builtin_amdgcn_s_setprio(0);
    __builtin_amdgcn_s_barrier();

    // ---- phase 2: quadrant (m2-3, n0-1); stage B r0 ----
    if (pf) stageB(nslot, t + 2, 0);
#pragma unroll
    for (int i = 0; i < 2; ++i)
#pragma unroll
      for (int kk = 0; kk < 2; ++kk)
        aa[i][kk] = lds_frag(Asl, arow + (2 + i) * 16, kk * 4 + chi);
    asm volatile("s_waitcnt lgkmcnt(0)" ::: "memory");
    __builtin_amdgcn_sched_barrier(0);
    __builtin_amdgcn_s_setprio(1);
#pragma unroll
    for (int i = 0; i < 2; ++i)
#pragma unroll
      for (int j = 0; j < 2; ++j)
#pragma unroll
        for (int kk = 0; kk < 2; ++kk)
          acc[2 + i][j] = __builtin_amdgcn_mfma_f32_16x16x32_bf16(aa[i][kk], bb[j][kk], acc[2 + i][j], 0, 0, 0);
    __builtin_amdgcn_s_setprio(0);
    __builtin_amdgcn_s_barrier();

    // ---- phase 3: quadrant (m2-3, n2-3); stage B r1; no new reads ----
    if (pf) stageB(nslot, t + 2, 1);
    __builtin_amdgcn_s_setprio(1);
#pragma unroll
    for (int i = 0; i < 2; ++i)
#pragma unroll
      for (int j = 2; j < 4; ++j)
#pragma unroll
        for (int kk = 0; kk < 2; ++kk)
          acc[2 + i][j] = __builtin_amdgcn_mfma_f32_16x16x32_bf16(aa[i][kk], bb[j][kk], acc[2 + i][j], 0, 0, 0);
    __builtin_amdgcn_s_setprio(0);
    // no barrier here: the loop-top boundary barrier covers it
  }
}

// ---------------- QKV projection (grid.z selects Q/K/V) ----------------
__global__ __launch_bounds__(512, 1) void qkv_gemm(const bf16_t* __restrict__ xb,
                                                   const bf16_t* __restrict__ wqb,
                                                   const bf16_t* __restrict__ wkb,
                                                   const bf16_t* __restrict__ wvb,
                                                   bf16_t* __restrict__ qraw,
                                                   bf16_t* __restrict__ kraw,
                                                   bf16_t* __restrict__ vt,
                                                   float* __restrict__ vout) {
  __shared__ __align__(16) bf16_t As3[3][256 * 64];
  __shared__ __align__(16) bf16_t Bs3[3][128 * 64];
  const int z = blockIdx.z;
  const bf16_t* Bm = (z == 0) ? wqb : ((z == 1) ? wkb : wvb);
  const int row0 = blockIdx.x * 256, col0 = blockIdx.y * 128;
  f32x4 acc[4][4] = {};
  gemm256_core(xb, Bm, As3, Bs3, row0, col0, acc);

  const int lane = threadIdx.x & 63, w = threadIdx.x >> 6;
  const int wm = w >> 1, wn = w & 1;
#pragma unroll
  for (int i = 0; i < 4; ++i) {
#pragma unroll
    for (int j = 0; j < 4; ++j) {
      const int gr0 = row0 + wm * 64 + i * 16 + (lane >> 4) * 4;  // 4 consecutive (b,s) rows
      const int gc = col0 + wn * 64 + j * 16 + (lane & 15);       // nh*128+hd col
      const int b = gr0 >> 11, s0 = gr0 & (CS - 1);
      const int nh = gc >> 7, hd = gc & (CHD - 1);
      if (z == 2) {
#pragma unroll
        for (int r = 0; r < 4; ++r) {
          const size_t idx = ((size_t)(b * CNH + nh) * CS + s0 + r) * CHD + hd;
          vout[idx] = acc[i][j][r];  // f32 v output (B,NH,S,HD)
        }
        bf16x4v pv = {(bf16_t)acc[i][j][0], (bf16_t)acc[i][j][1],
                      (bf16_t)acc[i][j][2], (bf16_t)acc[i][j][3]};
        *(bf16x4v*)(vt + ((size_t)(b * CNH + nh) * CHD + hd) * CS + s0) = pv;  // V^T bf16
      } else {
        bf16_t* dst = (z == 0) ? qraw : kraw;
#pragma unroll
        for (int r = 0; r < 4; ++r) {
          const size_t idx = ((size_t)(b * CNH + nh) * CS + s0 + r) * CHD + hd;
          dst[idx] = (bf16_t)acc[i][j][r];
        }
      }
    }
  }
}

// ---------------- output projection y = ob * Wo^T ----------------
__global__ __launch_bounds__(512, 1) void y_gemm(const bf16_t* __restrict__ ob,
                                                 const bf16_t* __restrict__ wob,
                                                 float* __restrict__ yout) {
  __shared__ __align__(16) bf16_t As3[3][256 * 64];
  __shared__ __align__(16) bf16_t Bs3[3][128 * 64];
  const int row0 = blockIdx.x * 256, col0 = blockIdx.y * 128;
  f32x4 acc[4][4] = {};
  gemm256_core(ob, wob, As3, Bs3, row0, col0, acc);
  const int lane = threadIdx.x & 63, w = threadIdx.x >> 6;
  const int wm = w >> 1, wn = w & 1;
#pragma unroll
  for (int i = 0; i < 4; ++i)
#pragma unroll
    for (int j = 0; j < 4; ++j)
#pragma unroll
      for (int r = 0; r < 4; ++r) {
        const int gr = row0 + wm * 64 + i * 16 + (lane >> 4) * 4 + r;
        const int gc = col0 + wn * 64 + j * 16 + (lane & 15);
        yout[(size_t)gr * CH + gc] = acc[i][j][r];
      }
}

// ---------------- RoPE (vectorized bf16x8; writes f32 k output) ----------------
__global__ __launch_bounds__(256) void rope_kernel(bf16_t* __restrict__ qraw,
                                                   bf16_t* __restrict__ kraw,
                                                   const float* __restrict__ cosd,
                                                   const float* __restrict__ sind,
                                                   float* __restrict__ kout) {
  const int gid = blockIdx.x * 256 + threadIdx.x;  // over B*NH*S*8 groups of 8 pairs
  const int isK = blockIdx.y;
  bf16_t* p = isK ? kraw : qraw;
  const int row = gid >> 3, d0 = (gid & 7) << 3;
  const int s = row & (CS - 1);
  const size_t base = (size_t)row * CHD;
  bf16x8 v1 = *(bf16x8*)(p + base + d0);
  bf16x8 v2 = *(bf16x8*)(p + base + d0 + 64);
  float c[8], sn[8];
  *(float4*)(c)      = *(const float4*)(cosd + s * CHD + d0);
  *(float4*)(c + 4)  = *(const float4*)(cosd + s * CHD + d0 + 4);
  *(float4*)(sn)     = *(const float4*)(sind + s * CHD + d0);
  *(float4*)(sn + 4) = *(const float4*)(sind + s * CHD + d0 + 4);
  float f1[8], f2[8];
  bf16x8 o1, o2;
#pragma unroll
  for (int i = 0; i < 8; ++i) {
    const float x1 = (float)v1[i], x2 = (float)v2[i];
    f1[i] = x1 * c[i] - x2 * sn[i];
    f2[i] = x2 * c[i] + x1 * sn[i];
    o1[i] = (bf16_t)f1[i];
    o2[i] = (bf16_t)f2[i];
  }
  *(bf16x8*)(p + base + d0) = o1;
  *(bf16x8*)(p + base + d0 + 64) = o2;
  if (isK) {
    *(float4*)(kout + base + d0)          = *(float4*)(f1);
    *(float4*)(kout + base + d0 + 4)      = *(float4*)(f1 + 4);
    *(float4*)(kout + base + d0 + 64)     = *(float4*)(f2);
    *(float4*)(kout + base + d0 + 64 + 4) = *(float4*)(f2 + 4);
  }
}

// ---------------- flash attention (unchanged from R2) ----------------
__global__ __launch_bounds__(256) void attn_kernel(const bf16_t* __restrict__ qb,
                                                   const bf16_t* __restrict__ kb,
                                                   const bf16_t* __restrict__ vt,
                                                   bf16_t* __restrict__ ob) {
  __shared__ __align__(16) bf16_t Ks[2][64 * 128];   // [kv][hd], 16 chunks/row, XOR-swz
  __shared__ __align__(16) bf16_t Vs[2][128 * 64];   // [hd][kv], 8 chunks/row, XOR-swz
  __shared__ __align__(16) bf16_t Ps[4][16 * 64];    // per-wave [q][kv], 8 chunks/row, XOR-swz
  const int tid = threadIdx.x, lane = tid & 63, w = tid >> 6;

  const int swz = (blockIdx.x & 7) * 256 + (blockIdx.x >> 3);
  const int bh = swz >> 5;
  const int qt = 31 - (swz & 31);

  const int b = bh >> 4, nh = bh & (CNH - 1);
  const size_t kvbase_g = (size_t)bh * CS * CHD;
  const bf16_t* vbh = vt + (size_t)bh * CHD * CS;
  const int q0w = qt * 64 + w * 16;

  bf16x8 aq[4];
  {
    const bf16_t* qp = qb + kvbase_g + (size_t)(q0w + (lane & 15)) * CHD + (lane >> 4) * 8;
#pragma unroll
    for (int kf = 0; kf < 4; ++kf) aq[kf] = *(const bf16x8*)(qp + kf * 32);
  }

  float m_[4], l_[4];
  f32x4 o_[8];
  const f32x4 zf = {0.f, 0.f, 0.f, 0.f};
#pragma unroll
  for (int r = 0; r < 4; ++r) { m_[r] = -INFINITY; l_[r] = 0.f; }
#pragma unroll
  for (int h = 0; h < 8; ++h) o_[h] = zf;

  auto stage = [&](int buf, int kt) {
    const bf16_t* kbase = kb + kvbase_g + (size_t)kt * 64 * CHD;
#pragma unroll
    for (int i = 0; i < 4; ++i) {
      const int c = i * 256 + w * 64 + lane;
      const int r = c >> 4, ck = c & 15;
      g2l16(kbase + (size_t)r * CHD + ((ck ^ (r & 7)) << 3),
            &Ks[buf][(size_t)(i * 256 + w * 64) * 8]);
    }
#pragma unroll
    for (int i = 0; i < 4; ++i) {
      const int c = i * 256 + w * 64 + lane;
      const int r = c >> 3, ck = c & 7;
      g2l16(vbh + (size_t)r * CS + kt * 64 + ((ck ^ (r & 7)) << 3),
            &Vs[buf][(size_t)(i * 256 + w * 64) * 8]);
    }
  };

  const int nt = qt + 1;
  stage(0, 0);
  __syncthreads();
  int cur = 0;

  for (int kt = 0; kt < nt; ++kt) {
    if (kt + 1 < nt) stage(cur ^ 1, kt + 1);

    f32x4 sf[4] = {};
#pragma unroll
    for (int kf = 0; kf < 4; ++kf) {
#pragma unroll
      for (int cf = 0; cf < 4; ++cf) {
        const int krow = cf * 16 + (lane & 15);
        const int lc = kf * 4 + (lane >> 4);
        bf16x8 bk = *(const bf16x8*)(&Ks[cur][krow * 128 + ((lc ^ (krow & 7)) << 3)]);
        sf[cf] = __builtin_amdgcn_mfma_f32_16x16x32_bf16(aq[kf], bk, sf[cf], 0, 0, 0);
      }
    }

    const int kvb = kt * 64;
    const bool diag = (kt == nt - 1);
    float tmax[4];
#pragma unroll
    for (int r = 0; r < 4; ++r) tmax[r] = -INFINITY;
#pragma unroll
    for (int cf = 0; cf < 4; ++cf) {
      const int kv = kvb + cf * 16 + (lane & 15);
#pragma unroll
      for (int r = 0; r < 4; ++r) {
        const int qr = q0w + (lane >> 4) * 4 + r;
        float xv = sf[cf][r] * CSCALE;
        if (diag && kv > qr) xv = -INFINITY;
        sf[cf][r] = xv;
        tmax[r] = fmaxf(tmax[r], xv);
      }
    }
#pragma unroll
    for (int off = 1; off < 16; off <<= 1)
#pragma unroll
      for (int r = 0; r < 4; ++r)
        tmax[r] = fmaxf(tmax[r], __shfl_xor(tmax[r], off, 64));

    bool need = false;
#pragma unroll
    for (int r = 0; r < 4; ++r) need |= (tmax[r] - m_[r]) > 8.0f;
    if (__any(need)) {
#pragma unroll
      for (int r = 0; r < 4; ++r) {
        const float mn = fmaxf(m_[r], tmax[r]);
        const float corr = exp2f((m_[r] - mn) * CL2E);
        m_[r] = mn;
        l_[r] *= corr;
#pragma unroll
        for (int h = 0; h < 8; ++h) o_[h][r] *= corr;
      }
    }

    float psum[4] = {0.f, 0.f, 0.f, 0.f};
#pragma unroll
    for (int cf = 0; cf < 4; ++cf) {
#pragma unroll
      for (int r = 0; r < 4; ++r) {
        const float pv = exp2f((sf[cf][r] - m_[r]) * CL2E);
        psum[r] += pv;
        const int prow = (lane >> 4) * 4 + r;
        const int col = cf * 16 + (lane & 15);
        Ps[w][prow * 64 + (((col >> 3) ^ (prow & 7)) << 3) + (col & 7)] = (bf16_t)pv;
      }
    }
#pragma unroll
    for (int off = 1; off < 16; off <<= 1)
#pragma unroll
      for (int r = 0; r < 4; ++r)
        psum[r] += __shfl_xor(psum[r], off, 64);
#pragma unroll
    for (int r = 0; r < 4; ++r) l_[r] += psum[r];

#pragma unroll
    for (int kf = 0; kf < 2; ++kf) {
      const int prow = lane & 15;
      const int lc = kf * 4 + (lane >> 4);
      bf16x8 ap = *(const bf16x8*)(&Ps[w][prow * 64 + ((lc ^ (prow & 7)) << 3)]);
#pragma unroll
      for (int hf = 0; hf < 8; ++hf) {
        const int vrow = hf * 16 + (lane & 15);
        bf16x8 bv = *(const bf16x8*)(&Vs[cur][vrow * 64 + ((lc ^ (vrow & 7)) << 3)]);
        o_[hf] = __builtin_amdgcn_mfma_f32_16x16x32_bf16(ap, bv, o_[hf], 0, 0, 0);
      }
    }

    __syncthreads();
    cur ^= 1;
  }

#pragma unroll
  for (int r = 0; r < 4; ++r) l_[r] = 1.0f / l_[r];
  const size_t obase = (size_t)b * CS * CH;
#pragma unroll
  for (int hf = 0; hf < 8; ++hf) {
#pragma unroll
    for (int r = 0; r < 4; ++r) {
      const int qr = q0w + (lane >> 4) * 4 + r;
      const int col = nh * CHD + hf * 16 + (lane & 15);
      ob[obase + (size_t)qr * CH + col] = (bf16_t)(o_[hf][r] * l_[r]);
    }
  }
}

extern "C" void kernel_launch(void* const* d_in, const int* in_sizes, int n_in,
                              void* d_out, int out_size, void* d_ws, size_t ws_size,
                              hipStream_t stream) {
  const float* x    = (const float*)d_in[0];
  const float* cosd = (const float*)d_in[1];
  const float* sind = (const float*)d_in[2];
  // d_in[3] = mask (causal, hardcoded)
  const float* Wq = (const float*)d_in[4];
  const float* Wk = (const float*)d_in[5];
  const float* Wv = (const float*)d_in[6];
  const float* Wo = (const float*)d_in[7];

  float* yout = (float*)d_out;
  float* kout = yout + (size_t)CM * CH;
  float* vout = kout + (size_t)CM * CH;

  char* ws = (char*)d_ws;
  size_t off = 0;
  auto wsalloc = [&](size_t bytes) {
    void* p = ws + off;
    off += (bytes + 255) & ~(size_t)255;
    return p;
  };
  bf16_t* xb   = (bf16_t*)wsalloc((size_t)CM * CH * 2);
  bf16_t* wqb  = (bf16_t*)wsalloc((size_t)CH * CH * 2);
  bf16_t* wkb  = (bf16_t*)wsalloc((size_t)CH * CH * 2);
  bf16_t* wvb  = (bf16_t*)wsalloc((size_t)CH * CH * 2);
  bf16_t* wob  = (bf16_t*)wsalloc((size_t)CH * CH * 2);
  bf16_t* qraw = (bf16_t*)wsalloc((size_t)CM * CH * 2);  // -> RoPE'd q (in-place)
  bf16_t* kraw = (bf16_t*)wsalloc((size_t)CM * CH * 2);  // -> RoPE'd k (in-place)
  bf16_t* vt   = (bf16_t*)wsalloc((size_t)CM * CH * 2);  // V^T [bh][hd][S]
  bf16_t* ob   = (bf16_t*)wsalloc((size_t)CM * CH * 2);  // attn out (B*S, H)

  cvt_kernel<<<CM * CH / 4 / 256, 256, 0, stream>>>(x, xb, CM * CH / 4);
  cvt_kernel<<<CH * CH / 4 / 256, 256, 0, stream>>>(Wq, wqb, CH * CH / 4);
  cvt_kernel<<<CH * CH / 4 / 256, 256, 0, stream>>>(Wk, wkb, CH * CH / 4);
  cvt_kernel<<<CH * CH / 4 / 256, 256, 0, stream>>>(Wv, wvb, CH * CH / 4);
  cvt_kernel<<<CH * CH / 4 / 256, 256, 0, stream>>>(Wo, wob, CH * CH / 4);

  qkv_gemm<<<dim3(CM / 256, CH / 128, 3), 512, 0, stream>>>(xb, wqb, wkb, wvb,
                                                            qraw, kraw, vt, vout);
  rope_kernel<<<dim3(CB * CNH * CS * 8 / 256, 2), 256, 0, stream>>>(qraw, kraw, cosd,
                                                                    sind, kout);
  attn_kernel<<<CS / 64 * CB * CNH, 256, 0, stream>>>(qraw, kraw, vt, ob);
  y_gemm<<<dim3(CM / 256, CH / 128), 512, 0, stream>>>(ob, wob, yout);
}